// Round 11
// baseline (282.855 us; speedup 1.0000x reference)
//
#include <hip/hip_runtime.h>
#include <math.h>

// Round 19: two attributable changes vs R18 (271.9us):
// 1) D1+D2 merged into ONE dispatch (prep_mt): Mt does the bf16 hi/lo split
//    INLINE during staging (reg-stage f32 Wq/Wk -> split -> ds_write, same
//    swizzled positions, bitwise-identical Mt) so it no longer depends on
//    prep outputs. Blocks: 0..8191 X->f16 | 8192..9215 WvT | 9216..9279 Mt.
//    Removes one ~15us inter-dispatch gap.
// 2) Deep body: uniform 1-stage-call/phase (m196: coarse load bunching hurts).
//    p0:A(t+1,kh0) p1:B(t+1,kh0) p2:A(t+1,kh1) p3:B(t+1,kh1); counted waits
//    re-derived: steady WAITV(4) [BMQ=2] / WAITV(3) [BMQ=1] at p1/p3 ends.
//   D1 prep_mt : X->f16 || WvT || Mt (inline-split 128^2)
//   D2 tv8d    : T || Vt (deep 256^2, 128KB)
//   D3 scd     : Sc = T . Xf^T -> fp32 (deep)
//   D4 softmax : P = softmax(Sc) -> f16
//   D5 pvd     : out = P . Vt^T (deep BM=128, 96KB)

typedef __bf16 bf16;
typedef _Float16 f16;
typedef __bf16 bf16x8 __attribute__((ext_vector_type(8)));
typedef _Float16 f16x4 __attribute__((ext_vector_type(4)));
typedef _Float16 f16x8 __attribute__((ext_vector_type(8)));
typedef float  f32x4  __attribute__((ext_vector_type(4)));

__device__ inline f32x4 mfma16(bf16x8 a, bf16x8 b, f32x4 c) {
    return __builtin_amdgcn_mfma_f32_16x16x32_bf16(a, b, c, 0, 0, 0);
}
__device__ inline f32x4 mfma16(f16x8 a, f16x8 b, f32x4 c) {
    return __builtin_amdgcn_mfma_f32_16x16x32_f16(a, b, c, 0, 0, 0);
}

#define AS1 __attribute__((address_space(1)))
#define AS3 __attribute__((address_space(3)))

template<typename E>
__device__ inline void async_load16(const E* g, void* l) {
    __builtin_amdgcn_global_load_lds((const AS1 unsigned int*)g,
                                     (AS3 unsigned int*)l, 16, 0, 0);
}

#define SBAR()   __builtin_amdgcn_s_barrier()
#define WAITV(n) asm volatile("s_waitcnt vmcnt(" #n ")" ::: "memory")
#define WAITL()  asm volatile("s_waitcnt lgkmcnt(0)")

// XCD-aware bijective tile swizzle (nwg % 8 == 0).
__device__ inline void xcd_swz(int nwg, int gx, int& bx, int& by) {
    const int flat = by * gx + bx;
    const int s = (flat & 7) * (nwg >> 3) + (flat >> 3);
    bx = s % gx;
    by = s / gx;
}

// ================= deep (BMQ*128)x256 f16 GEMM — uniform staging ===========
// Per tile 4 phases; ONE stage call per phase (A kh0 | B kh0 | A kh1 | B kh1).
// Counted waits: steady WAITV(aA+2) at p1-end (certifies A/B kh1 of tile t)
// and p3-end (certifies A/B kh0 of tile t+1). aA = BMQ loads per stageA.
template<int OUT_MODE, int BMQ>
__device__ __forceinline__ void gemm_deep_body(
    char* __restrict__ smraw,
    const f16* __restrict__ A, const f16* __restrict__ B,
    float* __restrict__ Cf, f16* __restrict__ Ch,
    int K, int lda, int ldb, int ldc,
    long long sA, long long sB, long long sC,
    int bx, int by, int bz)
{
    constexpr int ACH   = BMQ * 8192;
    constexpr int BOFF  = 2 * ACH;
    constexpr int BUFSZ = 2 * ACH + 32768;
    constexpr int nI    = 4 * BMQ;

    A += (long long)bz * sA;
    B += (long long)bz * sB;

    const int tid  = threadIdx.x;
    const int lane = tid & 63;
    const int wave = tid >> 6;
    const int quad = lane >> 4;
    const int l16  = lane & 15;
    const int wm   = wave >> 2;
    const int wn   = wave & 3;

    const long long rowA0 = (long long)by * (BMQ * 128);
    const long long colB0 = (long long)bx * 256;

    const int line0 = tid >> 3;
    const int slog  = (tid & 7) ^ (line0 & 7);
    const int r0s   = line0 * 2 + (slog >> 2);
    const int c0s   = (slog & 3) * 8;

    const f16* aSrc0 = A + (rowA0 + r0s) * lda + c0s;
    const f16* aSrc1 = A + (rowA0 + 128 + r0s) * lda + c0s;
    const f16* bSrc0 = B + (colB0 + r0s) * ldb + c0s;
    const f16* bSrc1 = B + (colB0 + 128 + r0s) * ldb + c0s;

    const int nt = K >> 6;

    auto stageA = [&](int t, int kh) {
        char* dst = smraw + (t & 1) * BUFSZ + kh * ACH;
        const int k0 = t * 64 + kh * 32;
        async_load16(aSrc0 + k0, dst + tid * 16);
        if constexpr (BMQ == 2) async_load16(aSrc1 + k0, dst + 8192 + tid * 16);
    };
    auto stageB = [&](int t, int kh) {
        char* dst = smraw + (t & 1) * BUFSZ + BOFF + kh * 16384;
        const int k0 = t * 64 + kh * 32;
        async_load16(bSrc0 + k0, dst + tid * 16);
        async_load16(bSrc1 + k0, dst + 8192 + tid * 16);
    };

    const int h    = l16 >> 1;
    const int lofs = h * 128 + ((((l16 & 1) * 4 + quad) ^ h) << 4);
    const int aoff = wm * (ACH / 2) + lofs;
    const int boff = BOFF + wn * 4096 + lofs;

    f32x4 acc[nI][4];
#pragma unroll
    for (int i = 0; i < nI; i++)
#pragma unroll
        for (int j = 0; j < 4; j++) acc[i][j] = (f32x4){0.f, 0.f, 0.f, 0.f};

    // prologue: tile0 fully staged; certify kh0 pair (A00,B00), keep kh1 in flight
    stageA(0, 0); stageB(0, 0); stageA(0, 1); stageB(0, 1);
    if constexpr (BMQ == 2) WAITV(4); else WAITV(3);
    SBAR();

    for (int t = 0; t < nt; t++) {
        const char* buf = smraw + (t & 1) * BUFSZ;
        f16x8 av[nI], bv[2];

        // ---- p0: reads A-kh0 + B(j01,kh0); stage A(t+1,kh0); 16/8 MFMA ----
#pragma unroll
        for (int i = 0; i < nI; i++) av[i] = *(const f16x8*)(buf + aoff + i * 1024);
        bv[0] = *(const f16x8*)(buf + boff);
        bv[1] = *(const f16x8*)(buf + boff + 1024);
        if (t + 1 < nt) stageA(t + 1, 0);
        SBAR();
        WAITL();
        __builtin_amdgcn_s_setprio(1);
#pragma unroll
        for (int i = 0; i < nI; i++) {
            acc[i][0] = mfma16(av[i], bv[0], acc[i][0]);
            acc[i][1] = mfma16(av[i], bv[1], acc[i][1]);
        }
        __builtin_amdgcn_s_setprio(0);
        SBAR();

        // ---- p1: reads B(j23,kh0); stage B(t+1,kh0); certify kh1(t) ----
        bv[0] = *(const f16x8*)(buf + boff + 2048);
        bv[1] = *(const f16x8*)(buf + boff + 3072);
        if (t + 1 < nt) stageB(t + 1, 0);
        SBAR();
        WAITL();
        __builtin_amdgcn_s_setprio(1);
#pragma unroll
        for (int i = 0; i < nI; i++) {
            acc[i][2] = mfma16(av[i], bv[0], acc[i][2]);
            acc[i][3] = mfma16(av[i], bv[1], acc[i][3]);
        }
        __builtin_amdgcn_s_setprio(0);
        if (t + 1 < nt) { if constexpr (BMQ == 2) WAITV(4); else WAITV(3); }
        else { WAITV(0); }
        SBAR();

        // ---- p2: reads A-kh1 + B(j01,kh1); stage A(t+1,kh1) ----
#pragma unroll
        for (int i = 0; i < nI; i++) av[i] = *(const f16x8*)(buf + ACH + aoff + i * 1024);
        bv[0] = *(const f16x8*)(buf + 16384 + boff);
        bv[1] = *(const f16x8*)(buf + 16384 + boff + 1024);
        if (t + 1 < nt) stageA(t + 1, 1);
        SBAR();
        WAITL();
        __builtin_amdgcn_s_setprio(1);
#pragma unroll
        for (int i = 0; i < nI; i++) {
            acc[i][0] = mfma16(av[i], bv[0], acc[i][0]);
            acc[i][1] = mfma16(av[i], bv[1], acc[i][1]);
        }
        __builtin_amdgcn_s_setprio(0);
        SBAR();

        // ---- p3: reads B(j23,kh1); stage B(t+1,kh1); certify kh0(t+1) ----
        bv[0] = *(const f16x8*)(buf + 16384 + boff + 2048);
        bv[1] = *(const f16x8*)(buf + 16384 + boff + 3072);
        if (t + 1 < nt) stageB(t + 1, 1);
        SBAR();
        WAITL();
        __builtin_amdgcn_s_setprio(1);
#pragma unroll
        for (int i = 0; i < nI; i++) {
            acc[i][2] = mfma16(av[i], bv[0], acc[i][2]);
            acc[i][3] = mfma16(av[i], bv[1], acc[i][3]);
        }
        __builtin_amdgcn_s_setprio(0);
        if (t + 1 < nt) { if constexpr (BMQ == 2) WAITV(4); else WAITV(3); }
        else { WAITV(0); }
        SBAR();
    }

    if constexpr (OUT_MODE == 2) {
        auto tr = (f16(*)[72])smraw;
        const int batch = (int)(rowA0 >> 11);
        const long long rib = rowA0 & 2047;
        const int c  = tid >> 1;
        const int r0 = (tid & 1) << 5;
#pragma unroll
        for (int h2 = 0; h2 < 2; h2++)
#pragma unroll
            for (int iq = 0; iq < 2; iq++) {
                __syncthreads();
                if (wm == h2) {
#pragma unroll
                    for (int i2 = 0; i2 < 4; i2++)
#pragma unroll
                        for (int j = 0; j < 4; j++)
#pragma unroll
                            for (int e = 0; e < 4; e++)
                                tr[wn * 64 + j * 16 + l16][i2 * 16 + quad * 4 + e] =
                                    (f16)acc[iq * 4 + i2][j][e];
                }
                __syncthreads();
                f16* vt = Ch + (long long)batch * 1024 * 2048 +
                          (long long)(colB0 + c) * ldc + rib + h2 * 128 + iq * 64 + r0;
#pragma unroll
                for (int u = 0; u < 32; u += 8)
                    *(f16x8*)(vt + u) = *(const f16x8*)&tr[c][r0 + u];
            }
        return;
    }

    const long long cOff = (long long)bz * sC +
                           (rowA0 + wm * (BMQ * 64) + quad * 4) * (long long)ldc +
                           colB0 + wn * 64 + l16;
#pragma unroll
    for (int i = 0; i < nI; i++)
#pragma unroll
        for (int e = 0; e < 4; e++) {
            const long long ro = cOff + (long long)(i * 16 + e) * ldc;
            if (OUT_MODE == 0) {
                float* rp = Cf + ro;
#pragma unroll
                for (int j = 0; j < 4; j++) rp[j * 16] = acc[i][j][e];
            } else {
                f16* rp = Ch + ro;
#pragma unroll
                for (int j = 0; j < 4; j++) rp[j * 16] = (f16)acc[i][j][e];
            }
        }
}

__global__ __launch_bounds__(512, 2) void tv8d(
    const f16* __restrict__ Xf, const f16* __restrict__ Mt_f,
    const f16* __restrict__ Wvt_f, f16* __restrict__ T, f16* __restrict__ Vt)
{
    extern __shared__ char smraw[];
    int bx = blockIdx.x, by = blockIdx.y;
    xcd_swz(256, 8, bx, by);
    if (bx < 4)
        gemm_deep_body<1, 2>(smraw, Xf, Mt_f, nullptr, T, 1024, 1024, 1024, 1024,
                             0, 0, 0, bx, by, 0);
    else
        gemm_deep_body<2, 2>(smraw, Xf, Wvt_f, nullptr, Vt, 1024, 1024, 1024, 2048,
                             0, 0, 0, bx - 4, by, 0);
}

template<int OUT_MODE, int BMQ>
__global__ __launch_bounds__(512, 2) void gemmd_k(
    const f16* __restrict__ A, const f16* __restrict__ B,
    float* __restrict__ Cf, f16* __restrict__ Ch,
    int K, int lda, int ldb, int ldc,
    long long sA, long long sB, long long sC)
{
    extern __shared__ char smraw[];
    int bx = blockIdx.x, by = blockIdx.y;
    xcd_swz(gridDim.x * gridDim.y, gridDim.x, bx, by);
    gemm_deep_body<OUT_MODE, BMQ>(smraw, A, B, Cf, Ch, K, lda, ldb, ldc,
                                  sA, sB, sC, bx, by, blockIdx.z);
}

// ============ 64KB fallback kernels (R13-verified; only if attrs fail) =====
template<int OUT_MODE, int BMQ>
__device__ __forceinline__ void gemm8_body(
    char* __restrict__ smraw,
    const f16* __restrict__ A, const f16* __restrict__ B,
    float* __restrict__ Cf, f16* __restrict__ Ch,
    int K, int lda, int ldb, int ldc,
    long long sA, long long sB, long long sC,
    int bx, int by, int bz)
{
    constexpr int B0OFF = BMQ * 8192;
    constexpr int B1OFF = B0OFF + 8192;
    constexpr int BUFSZ = B0OFF + 16384;

    A += (long long)bz * sA;
    B += (long long)bz * sB;

    const int tid  = threadIdx.x;
    const int lane = tid & 63;
    const int wave = tid >> 6;
    const int quad = lane >> 4;
    const int l16  = lane & 15;
    const int wm   = wave >> 2;
    const int wn   = wave & 3;

    const long long rowA0 = (long long)by * (BMQ * 128);
    const long long colB0 = (long long)bx * 256;

    const int line0 = tid >> 3;
    const int slog  = (tid & 7) ^ (line0 & 7);
    const int aRow0 = line0 * 2 + (slog >> 2);
    const int aCol0 = (slog & 3) * 8;
    const int bRow  = ((aRow0 >> 5) << 6) + (aRow0 & 31);

    const f16* aSrc0 = A + (rowA0 + aRow0) * lda + aCol0;
    const f16* aSrc1 = A + (rowA0 + 128 + aRow0) * lda + aCol0;
    const f16* b0Src = B + (colB0 + bRow) * ldb + aCol0;
    const f16* b1Src = b0Src + 32LL * ldb;

    const int dA0 = tid * 16, dA1 = 8192 + tid * 16;

    const int nt = K >> 5;

    auto stageA = [&](int t) {
        char* buf = smraw + (t & 1) * BUFSZ;
        async_load16(aSrc0 + t * 32, buf + dA0);
        if (BMQ == 2) async_load16(aSrc1 + t * 32, buf + dA1);
    };
    auto stageB0 = [&](int t) {
        char* buf = smraw + (t & 1) * BUFSZ;
        async_load16(b0Src + t * 32, buf + B0OFF + dA0);
    };
    auto stageB1 = [&](int t) {
        char* buf = smraw + (t & 1) * BUFSZ;
        async_load16(b1Src + t * 32, buf + B1OFF + dA0);
    };

    const int h    = l16 >> 1;
    const int lofs = h * 128 + ((((l16 & 1) * 4 + quad) ^ h) << 4);
    const int aoff = wm * (BMQ * 4096) + lofs;
    const int boff = wn * 2048 + lofs;

    f32x4 acc[4 * BMQ][4];
#pragma unroll
    for (int i = 0; i < 4 * BMQ; i++)
#pragma unroll
        for (int j = 0; j < 4; j++) acc[i][j] = (f32x4){0.f, 0.f, 0.f, 0.f};

    stageA(0); stageB0(0); stageB1(0);
    stageA(1); stageB0(1);
    if constexpr (BMQ == 2) WAITV(4); else WAITV(3);
    SBAR();

    for (int t = 0; t < nt; t++) {
        const char* buf = smraw + (t & 1) * BUFSZ;
        f16x8 av[4 * BMQ], bv[2];

#pragma unroll
        for (int i = 0; i < 4 * BMQ; i++) av[i] = *(const f16x8*)(buf + aoff + i * 1024);
#pragma unroll
        for (int j = 0; j < 2; j++) bv[j] = *(const f16x8*)(buf + B0OFF + boff + j * 1024);
        if (t + 1 < nt) stageB1(t + 1);
        SBAR();
        WAITL();
        __builtin_amdgcn_s_setprio(1);
#pragma unroll
        for (int i = 0; i < 4 * BMQ; i++) {
            acc[i][0] = mfma16(av[i], bv[0], acc[i][0]);
            acc[i][1] = mfma16(av[i], bv[1], acc[i][1]);
        }
        __builtin_amdgcn_s_setprio(0);
        if (t + 1 < nt) { if constexpr (BMQ == 2) WAITV(4); else WAITV(3); }
        else WAITV(0);
        SBAR();

#pragma unroll
        for (int j = 0; j < 2; j++) bv[j] = *(const f16x8*)(buf + B1OFF + boff + j * 1024);
        if (t + 2 < nt) { stageA(t + 2); stageB0(t + 2); }
        SBAR();
        WAITL();
        __builtin_amdgcn_s_setprio(1);
#pragma unroll
        for (int i = 0; i < 4 * BMQ; i++) {
            acc[i][2] = mfma16(av[i], bv[0], acc[i][2]);
            acc[i][3] = mfma16(av[i], bv[1], acc[i][3]);
        }
        __builtin_amdgcn_s_setprio(0);
        if (t + 2 < nt) { if constexpr (BMQ == 2) WAITV(4); else WAITV(3); }
        else if (t + 1 < nt) WAITV(1);
        SBAR();
    }

    if constexpr (OUT_MODE == 2) {
        auto tr = (f16(*)[72])smraw;
        const int batch = (int)(rowA0 >> 11);
        const long long rib = rowA0 & 2047;
        const int c  = tid >> 1;
        const int r0 = (tid & 1) << 5;
#pragma unroll
        for (int h2 = 0; h2 < 2; h2++)
#pragma unroll
            for (int iq = 0; iq < 2; iq++) {
                __syncthreads();
                if (wm == h2) {
#pragma unroll
                    for (int i2 = 0; i2 < 4; i2++)
#pragma unroll
                        for (int j = 0; j < 4; j++)
#pragma unroll
                            for (int e = 0; e < 4; e++)
                                tr[wn * 64 + j * 16 + l16][i2 * 16 + quad * 4 + e] =
                                    (f16)acc[iq * 4 + i2][j][e];
                }
                __syncthreads();
                f16* vt = Ch + (long long)batch * 1024 * 2048 +
                          (long long)(colB0 + c) * ldc + rib + h2 * 128 + iq * 64 + r0;
#pragma unroll
                for (int u = 0; u < 32; u += 8)
                    *(f16x8*)(vt + u) = *(const f16x8*)&tr[c][r0 + u];
            }
        return;
    }

    const long long cOff = (long long)bz * sC +
                           (rowA0 + wm * (BMQ * 64) + quad * 4) * (long long)ldc +
                           colB0 + wn * 64 + l16;
#pragma unroll
    for (int i = 0; i < 4 * BMQ; i++)
#pragma unroll
        for (int e = 0; e < 4; e++) {
            const long long ro = cOff + (long long)(i * 16 + e) * ldc;
            if (OUT_MODE == 0) {
                float* rp = Cf + ro;
#pragma unroll
                for (int j = 0; j < 4; j++) rp[j * 16] = acc[i][j][e];
            } else {
                f16* rp = Ch + ro;
#pragma unroll
                for (int j = 0; j < 4; j++) rp[j * 16] = (f16)acc[i][j][e];
            }
        }
}

__global__ __launch_bounds__(512, 2) void tv8(
    const f16* __restrict__ Xf, const f16* __restrict__ Mt_f,
    const f16* __restrict__ Wvt_f, f16* __restrict__ T, f16* __restrict__ Vt)
{
    extern __shared__ char smraw[];
    int bx = blockIdx.x, by = blockIdx.y;
    xcd_swz(256, 8, bx, by);
    if (bx < 4)
        gemm8_body<1, 2>(smraw, Xf, Mt_f, nullptr, T, 1024, 1024, 1024, 1024,
                         0, 0, 0, bx, by, 0);
    else
        gemm8_body<2, 2>(smraw, Xf, Wvt_f, nullptr, Vt, 1024, 1024, 1024, 2048,
                         0, 0, 0, bx - 4, by, 0);
}

template<int OUT_MODE, int BMQ>
__global__ __launch_bounds__(512, 2) void gemm8_k(
    const f16* __restrict__ A, const f16* __restrict__ B,
    float* __restrict__ Cf, f16* __restrict__ Ch,
    int K, int lda, int ldb, int ldc,
    long long sA, long long sB, long long sC)
{
    extern __shared__ char smraw[];
    int bx = blockIdx.x, by = blockIdx.y;
    xcd_swz(gridDim.x * gridDim.y, gridDim.x, bx, by);
    gemm8_body<OUT_MODE, BMQ>(smraw, A, B, Cf, Ch, K, lda, ldb, ldc, sA, sB, sC,
                              bx, by, blockIdx.z);
}

// ============ Mt body with INLINE bf16 split (reg-staged, 128^2 BK=32) =====
// Bitwise-identical to prep-split + gload_lds path: same swizzled source
// positions, same linear LDS layout, same hi/lo math, same MFMA order.
__device__ __forceinline__ void mt_body(
    char* __restrict__ smraw,
    const float* __restrict__ WkF, const float* __restrict__ WqF,
    f16* __restrict__ Mt_f, int bx, int by)
{
    constexpr int TILE = 8192;                 // 128 x 32 bf16
    const int tid  = threadIdx.x;
    const int lane = tid & 63;
    const int wave = tid >> 6;
    const int quad = lane >> 4;
    const int l16  = lane & 15;
    const int wm   = (wave >> 1) * 64;
    const int wn   = (wave & 1) * 64;

    const long long rowA0 = (long long)by * 128;
    const long long colB0 = (long long)bx * 128;

    int ofs[2], rr[2], cc8[2];
#pragma unroll
    for (int u = 0; u < 2; u++) {
        ofs[u] = (wave * 2 + u) * 1024 + lane * 16;
        const int s = ofs[u] >> 4;
        rr[u]  = s >> 2;                        // SPR = 4
        cc8[u] = (s & 3) ^ ((rr[u] >> 1) & 3);  // SPR=4 swizzle
    }

    f32x4 acc[4][4];
#pragma unroll
    for (int i = 0; i < 4; i++)
#pragma unroll
        for (int j = 0; j < 4; j++) acc[i][j] = (f32x4){0.f, 0.f, 0.f, 0.f};

    for (int k0 = 0; k0 < 1024; k0 += 32) {
#pragma unroll
        for (int u = 0; u < 2; u++) {
            const float* pa = WkF + (rowA0 + rr[u]) * 1024 + k0 + cc8[u] * 8;
            const float* pb = WqF + (colB0 + rr[u]) * 1024 + k0 + cc8[u] * 8;
            float4 a0 = *(const float4*)pa, a1 = *(const float4*)(pa + 4);
            float4 b0 = *(const float4*)pb, b1 = *(const float4*)(pb + 4);
            float va[8] = {a0.x, a0.y, a0.z, a0.w, a1.x, a1.y, a1.z, a1.w};
            float vb[8] = {b0.x, b0.y, b0.z, b0.w, b1.x, b1.y, b1.z, b1.w};
            bf16x8 ah, al, bh, bl;
#pragma unroll
            for (int e = 0; e < 8; e++) {
                bf16 hA = (bf16)va[e]; ah[e] = hA; al[e] = (bf16)(va[e] - (float)hA);
                bf16 hB = (bf16)vb[e]; bh[e] = hB; bl[e] = (bf16)(vb[e] - (float)hB);
            }
            *(bf16x8*)(smraw + 0 * TILE + ofs[u]) = ah;
            *(bf16x8*)(smraw + 1 * TILE + ofs[u]) = bh;
            *(bf16x8*)(smraw + 2 * TILE + ofs[u]) = al;
            *(bf16x8*)(smraw + 3 * TILE + ofs[u]) = bl;
        }
        __syncthreads();

        {
            const int kc8 = quad;               // BK=32: single kh
            bf16x8 a_hi[4], b_hi[4], a_lo[4], b_lo[4];
#pragma unroll
            for (int i = 0; i < 4; i++) {
                const int ra = wm + i * 16 + l16;
                const int rb = wn + i * 16 + l16;
                const int oa = ra * 64 + ((kc8 ^ ((ra >> 1) & 3)) << 4);
                const int ob = rb * 64 + ((kc8 ^ ((rb >> 1) & 3)) << 4);
                a_hi[i] = *(const bf16x8*)(smraw + 0 * TILE + oa);
                b_hi[i] = *(const bf16x8*)(smraw + 1 * TILE + ob);
                a_lo[i] = *(const bf16x8*)(smraw + 2 * TILE + oa);
                b_lo[i] = *(const bf16x8*)(smraw + 3 * TILE + ob);
            }
#pragma unroll
            for (int i = 0; i < 4; i++)
#pragma unroll
                for (int j = 0; j < 4; j++) {
                    acc[i][j] = mfma16(a_hi[i], b_hi[j], acc[i][j]);
                    acc[i][j] = mfma16(a_hi[i], b_lo[j], acc[i][j]);
                    acc[i][j] = mfma16(a_lo[i], b_hi[j], acc[i][j]);
                }
        }
        __syncthreads();
    }

    const long long cOff = (rowA0 + wm + quad * 4) * 1024 + colB0 + wn + l16;
#pragma unroll
    for (int i = 0; i < 4; i++)
#pragma unroll
        for (int e = 0; e < 4; e++) {
            f16* rp = Mt_f + cOff + (i * 16 + e) * 1024;
#pragma unroll
            for (int j = 0; j < 4; j++) rp[j * 16] = (f16)acc[i][j][e];
        }
}

// ---- D1: merged prep + Mt (all branches input-independent) ----
// blocks 0..8191: X->f16 | 8192..9215: Wv transpose->f16 | 9216..9279: Mt.
__global__ __launch_bounds__(256) void prep_mt(
    const float4* __restrict__ X, f16* __restrict__ Xf,
    const float* __restrict__ Wq, const float* __restrict__ Wk,
    const float* __restrict__ Wv,
    f16* __restrict__ Wvt_f, f16* __restrict__ Mt_f)
{
    extern __shared__ char smraw[];
    int b = blockIdx.x;
    if (b < 8192) {
        long long i = (long long)b * 256 + threadIdx.x;
        float4 v = X[i];
        f16x4 fv = {(f16)v.x, (f16)v.y, (f16)v.z, (f16)v.w};
        *(f16x4*)(Xf + 4 * i) = fv;
    } else if (b < 9216) {
        const int b3 = b - 8192;
        auto t = (float(*)[33])smraw;          // 32x33 f32 = 4224 B
        const int bx = (b3 & 31) * 32, by = (b3 >> 5) * 32;
        const int tx = threadIdx.x & 31, ty = threadIdx.x >> 5;
#pragma unroll
        for (int i = 0; i < 32; i += 8)
            t[ty + i][tx] = Wv[(long long)(by + ty + i) * 1024 + bx + tx];
        __syncthreads();
#pragma unroll
        for (int i = 0; i < 32; i += 8) {
            long long o = (long long)(bx + ty + i) * 1024 + by + tx;
            Wvt_f[o] = (f16)t[tx][ty + i];
        }
    } else {
        const int mb = b - 9216;               // 64 blocks, 8x8
        mt_body(smraw, Wk, Wq, Mt_f, mb & 7, mb >> 3);
    }
}

// ---- D4: row softmax fp32 -> f16, vectorized ----
__global__ __launch_bounds__(256) void softmax_f16(const float* __restrict__ S,
                                                   f16* __restrict__ P, int n)
{
    const long long row = blockIdx.x;
    const float4* p = (const float4*)(S + row * (long long)n);
    f16* q = P + row * (long long)n;
    const int tid = threadIdx.x;
    const int wv = tid >> 6, lane = tid & 63;

    float4 va = p[tid], vb = p[tid + 256];
    float v[8] = {va.x, va.y, va.z, va.w, vb.x, vb.y, vb.z, vb.w};
    float m = -3.4e38f;
#pragma unroll
    for (int i = 0; i < 8; i++) m = fmaxf(m, v[i]);
#pragma unroll
    for (int off = 32; off > 0; off >>= 1) m = fmaxf(m, __shfl_xor(m, off, 64));

    __shared__ float red[4];
    if (lane == 0) red[wv] = m;
    __syncthreads();
    m = fmaxf(fmaxf(red[0], red[1]), fmaxf(red[2], red[3]));

    float s = 0.f;
#pragma unroll
    for (int i = 0; i < 8; i++) { v[i] = __expf(v[i] - m); s += v[i]; }
#pragma unroll
    for (int off = 32; off > 0; off >>= 1) s += __shfl_xor(s, off, 64);
    __syncthreads();
    if (lane == 0) red[wv] = s;
    __syncthreads();
    s = red[0] + red[1] + red[2] + red[3];

    const float inv = 1.0f / s;
    f16x4 o0 = {(f16)(v[0] * inv), (f16)(v[1] * inv), (f16)(v[2] * inv), (f16)(v[3] * inv)};
    f16x4 o1 = {(f16)(v[4] * inv), (f16)(v[5] * inv), (f16)(v[6] * inv), (f16)(v[7] * inv)};
    *(f16x4*)(q + tid * 4) = o0;
    *(f16x4*)(q + 1024 + tid * 4) = o1;
}

extern "C" void kernel_launch(void* const* d_in, const int* in_sizes, int n_in,
                              void* d_out, int out_size, void* d_ws, size_t ws_size,
                              hipStream_t stream) {
    const float* X  = (const float*)d_in[0];   // [8192,1024]
    const float* Wq = (const float*)d_in[1];   // [1024,1024]
    const float* Wk = (const float*)d_in[2];
    const float* Wv = (const float*)d_in[3];
    float* out = (float*)d_out;                // [8192,1024]

    char* w = (char*)d_ws;
    const long long MB = 1024LL * 1024;
    f16*  Xf    = (f16*) (w + 0 * MB);     // 16 MB
    f16*  Wvt_f = (f16*) (w + 24 * MB);    // 2 MB (transposed)
    f16*  Mt_f  = (f16*) (w + 26 * MB);    // 2 MB
    f16*  T     = (f16*) (w + 28 * MB);    // 16 MB [8192,1024]
    f16*  Vt    = (f16*) (w + 44 * MB);    // 16 MB [4][1024][2048]
    float* Sc   = (float*)(w + 60 * MB);   // 64 MB
    f16*  P     = (f16*) (w + 124 * MB);   // 32 MB -> ends 156 MB

    static int deep_ok = -1;
    if (deep_ok < 0) {
        auto* pSc = gemmd_k<0, 2>;
        auto* pPv = gemmd_k<0, 1>;
        hipError_t e1 = hipFuncSetAttribute(
            reinterpret_cast<const void*>(tv8d),
            hipFuncAttributeMaxDynamicSharedMemorySize, 131072);
        hipError_t e2 = hipFuncSetAttribute(
            reinterpret_cast<const void*>(pSc),
            hipFuncAttributeMaxDynamicSharedMemorySize, 131072);
        hipError_t e3 = hipFuncSetAttribute(
            reinterpret_cast<const void*>(pPv),
            hipFuncAttributeMaxDynamicSharedMemorySize, 98304);
        deep_ok = (e1 == hipSuccess && e2 == hipSuccess && e3 == hipSuccess) ? 1 : 0;
    }

    dim3 blk(256);

    // D1: merged prep + Mt (one dispatch; 33280 B LDS covers Mt 32768 / WvT 4224)
    prep_mt<<<dim3(9280), blk, 33280, stream>>>(
        (const float4*)X, Xf, Wq, Wk, Wv, Wvt_f, Mt_f);

    if (deep_ok) {
        // D2: T || Vt (deep 256^2)
        tv8d<<<dim3(8, 32), dim3(512), 131072, stream>>>(Xf, Mt_f, Wvt_f, T, Vt);
        // D3: Sc = T . Xf^T per batch -> fp32
        gemmd_k<0, 2><<<dim3(8, 8, 4), dim3(512), 131072, stream>>>(
            T, Xf, Sc, nullptr, 1024, 1024, 1024, 2048,
            2048LL * 1024, 2048LL * 1024, 2048LL * 2048);
        // D4: softmax rows -> f16 P
        softmax_f16<<<dim3(4 * 2048), blk, 0, stream>>>(Sc, P, 2048);
        // D5: out = P . Vt^T (deep BM=128)
        gemmd_k<0, 1><<<dim3(4, 16, 4), dim3(512), 98304, stream>>>(
            P, Vt, out, nullptr, 2048, 2048, 2048, 1024,
            2048LL * 2048, 1024LL * 2048, 2048LL * 1024);
    } else {
        tv8<<<dim3(8, 32), dim3(512), 65536, stream>>>(Xf, Mt_f, Wvt_f, T, Vt);
        gemm8_k<0, 2><<<dim3(8, 8, 4), dim3(512), 65536, stream>>>(
            T, Xf, Sc, nullptr, 1024, 1024, 1024, 2048,
            2048LL * 1024, 2048LL * 1024, 2048LL * 2048);
        softmax_f16<<<dim3(4 * 2048), blk, 0, stream>>>(Sc, P, 2048);
        gemm8_k<0, 1><<<dim3(8, 16, 4), dim3(512), 49152, stream>>>(
            P, Vt, out, nullptr, 2048, 2048, 2048, 1024,
            2048LL * 2048, 1024LL * 2048, 2048LL * 1024);
    }
}

// Round 12
// 276.699 us; speedup vs baseline: 1.0222x; 1.0222x over previous
//
#include <hip/hip_runtime.h>
#include <math.h>

// Round 20: disentangle R19. REVERT the prep/Mt merge (R11: Mt blocks at grid
// tail + serial reg-split body = 81us vs 23us separate). KEEP R19's uniform
// 1-stage-call/phase deep body (budget arithmetic from R11 implies it saved
// ~32us across the GEMMs; this round attributes it cleanly vs R18's Sc=47.7).
//   D1 prep_all : X->f16 || Wq,Wk bf16-split || Wv transpose->f16
//   D2 mt       : Mt = Wk_s Wq_s^T (split-bf16 3-MFMA, 128^2, gload_lds)
//   D3 tv8d     : T || Vt (deep 256^2, 128KB, uniform staging)
//   D4 scd      : Sc = T . Xf^T -> fp32 (deep, uniform staging)
//   D5 softmax  : P = softmax(Sc) -> f16
//   D6 pvd      : out = P . Vt^T (deep BM=128, 96KB, uniform staging)

typedef __bf16 bf16;
typedef _Float16 f16;
typedef __bf16 bf16x8 __attribute__((ext_vector_type(8)));
typedef _Float16 f16x4 __attribute__((ext_vector_type(4)));
typedef _Float16 f16x8 __attribute__((ext_vector_type(8)));
typedef float  f32x4  __attribute__((ext_vector_type(4)));

template<typename E> struct vec8_of;
template<> struct vec8_of<bf16> { using type = bf16x8; };
template<> struct vec8_of<f16>  { using type = f16x8; };

__device__ inline f32x4 mfma16(bf16x8 a, bf16x8 b, f32x4 c) {
    return __builtin_amdgcn_mfma_f32_16x16x32_bf16(a, b, c, 0, 0, 0);
}
__device__ inline f32x4 mfma16(f16x8 a, f16x8 b, f32x4 c) {
    return __builtin_amdgcn_mfma_f32_16x16x32_f16(a, b, c, 0, 0, 0);
}

#define AS1 __attribute__((address_space(1)))
#define AS3 __attribute__((address_space(3)))

template<typename E>
__device__ inline void async_load16(const E* g, void* l) {
    __builtin_amdgcn_global_load_lds((const AS1 unsigned int*)g,
                                     (AS3 unsigned int*)l, 16, 0, 0);
}

#define SBAR()   __builtin_amdgcn_s_barrier()
#define WAITV(n) asm volatile("s_waitcnt vmcnt(" #n ")" ::: "memory")
#define WAITL()  asm volatile("s_waitcnt lgkmcnt(0)")

// XCD-aware bijective tile swizzle (nwg % 8 == 0).
__device__ inline void xcd_swz(int nwg, int gx, int& bx, int& by) {
    const int flat = by * gx + bx;
    const int s = (flat & 7) * (nwg >> 3) + (flat >> 3);
    bx = s % gx;
    by = s / gx;
}

// ======== deep (BMQ*128)x256 f16 GEMM — uniform 1-stage-call/phase ========
// p0:A(t+1,kh0) p1:B(t+1,kh0) p2:A(t+1,kh1) p3:B(t+1,kh1).
// Counted waits: steady WAITV(BMQ+2) at p1-end (certifies kh1 of t) and
// p3-end (certifies kh0 of t+1); tails drain to 0.
template<int OUT_MODE, int BMQ>
__device__ __forceinline__ void gemm_deep_body(
    char* __restrict__ smraw,
    const f16* __restrict__ A, const f16* __restrict__ B,
    float* __restrict__ Cf, f16* __restrict__ Ch,
    int K, int lda, int ldb, int ldc,
    long long sA, long long sB, long long sC,
    int bx, int by, int bz)
{
    constexpr int ACH   = BMQ * 8192;
    constexpr int BOFF  = 2 * ACH;
    constexpr int BUFSZ = 2 * ACH + 32768;
    constexpr int nI    = 4 * BMQ;

    A += (long long)bz * sA;
    B += (long long)bz * sB;

    const int tid  = threadIdx.x;
    const int lane = tid & 63;
    const int wave = tid >> 6;
    const int quad = lane >> 4;
    const int l16  = lane & 15;
    const int wm   = wave >> 2;
    const int wn   = wave & 3;

    const long long rowA0 = (long long)by * (BMQ * 128);
    const long long colB0 = (long long)bx * 256;

    const int line0 = tid >> 3;
    const int slog  = (tid & 7) ^ (line0 & 7);
    const int r0s   = line0 * 2 + (slog >> 2);
    const int c0s   = (slog & 3) * 8;

    const f16* aSrc0 = A + (rowA0 + r0s) * lda + c0s;
    const f16* aSrc1 = A + (rowA0 + 128 + r0s) * lda + c0s;
    const f16* bSrc0 = B + (colB0 + r0s) * ldb + c0s;
    const f16* bSrc1 = B + (colB0 + 128 + r0s) * ldb + c0s;

    const int nt = K >> 6;

    auto stageA = [&](int t, int kh) {
        char* dst = smraw + (t & 1) * BUFSZ + kh * ACH;
        const int k0 = t * 64 + kh * 32;
        async_load16(aSrc0 + k0, dst + tid * 16);
        if constexpr (BMQ == 2) async_load16(aSrc1 + k0, dst + 8192 + tid * 16);
    };
    auto stageB = [&](int t, int kh) {
        char* dst = smraw + (t & 1) * BUFSZ + BOFF + kh * 16384;
        const int k0 = t * 64 + kh * 32;
        async_load16(bSrc0 + k0, dst + tid * 16);
        async_load16(bSrc1 + k0, dst + 8192 + tid * 16);
    };

    const int h    = l16 >> 1;
    const int lofs = h * 128 + ((((l16 & 1) * 4 + quad) ^ h) << 4);
    const int aoff = wm * (ACH / 2) + lofs;
    const int boff = BOFF + wn * 4096 + lofs;

    f32x4 acc[nI][4];
#pragma unroll
    for (int i = 0; i < nI; i++)
#pragma unroll
        for (int j = 0; j < 4; j++) acc[i][j] = (f32x4){0.f, 0.f, 0.f, 0.f};

    // prologue: tile0 fully staged; certify kh0 pair, keep kh1 in flight
    stageA(0, 0); stageB(0, 0); stageA(0, 1); stageB(0, 1);
    if constexpr (BMQ == 2) WAITV(4); else WAITV(3);
    SBAR();

    for (int t = 0; t < nt; t++) {
        const char* buf = smraw + (t & 1) * BUFSZ;
        f16x8 av[nI], bv[2];

        // ---- p0: reads A-kh0 + B(j01,kh0); stage A(t+1,kh0) ----
#pragma unroll
        for (int i = 0; i < nI; i++) av[i] = *(const f16x8*)(buf + aoff + i * 1024);
        bv[0] = *(const f16x8*)(buf + boff);
        bv[1] = *(const f16x8*)(buf + boff + 1024);
        if (t + 1 < nt) stageA(t + 1, 0);
        SBAR();
        WAITL();
        __builtin_amdgcn_s_setprio(1);
#pragma unroll
        for (int i = 0; i < nI; i++) {
            acc[i][0] = mfma16(av[i], bv[0], acc[i][0]);
            acc[i][1] = mfma16(av[i], bv[1], acc[i][1]);
        }
        __builtin_amdgcn_s_setprio(0);
        SBAR();

        // ---- p1: reads B(j23,kh0); stage B(t+1,kh0); certify kh1(t) ----
        bv[0] = *(const f16x8*)(buf + boff + 2048);
        bv[1] = *(const f16x8*)(buf + boff + 3072);
        if (t + 1 < nt) stageB(t + 1, 0);
        SBAR();
        WAITL();
        __builtin_amdgcn_s_setprio(1);
#pragma unroll
        for (int i = 0; i < nI; i++) {
            acc[i][2] = mfma16(av[i], bv[0], acc[i][2]);
            acc[i][3] = mfma16(av[i], bv[1], acc[i][3]);
        }
        __builtin_amdgcn_s_setprio(0);
        if (t + 1 < nt) { if constexpr (BMQ == 2) WAITV(4); else WAITV(3); }
        else { WAITV(0); }
        SBAR();

        // ---- p2: reads A-kh1 + B(j01,kh1); stage A(t+1,kh1) ----
#pragma unroll
        for (int i = 0; i < nI; i++) av[i] = *(const f16x8*)(buf + ACH + aoff + i * 1024);
        bv[0] = *(const f16x8*)(buf + 16384 + boff);
        bv[1] = *(const f16x8*)(buf + 16384 + boff + 1024);
        if (t + 1 < nt) stageA(t + 1, 1);
        SBAR();
        WAITL();
        __builtin_amdgcn_s_setprio(1);
#pragma unroll
        for (int i = 0; i < nI; i++) {
            acc[i][0] = mfma16(av[i], bv[0], acc[i][0]);
            acc[i][1] = mfma16(av[i], bv[1], acc[i][1]);
        }
        __builtin_amdgcn_s_setprio(0);
        SBAR();

        // ---- p3: reads B(j23,kh1); stage B(t+1,kh1); certify kh0(t+1) ----
        bv[0] = *(const f16x8*)(buf + 16384 + boff + 2048);
        bv[1] = *(const f16x8*)(buf + 16384 + boff + 3072);
        if (t + 1 < nt) stageB(t + 1, 1);
        SBAR();
        WAITL();
        __builtin_amdgcn_s_setprio(1);
#pragma unroll
        for (int i = 0; i < nI; i++) {
            acc[i][2] = mfma16(av[i], bv[0], acc[i][2]);
            acc[i][3] = mfma16(av[i], bv[1], acc[i][3]);
        }
        __builtin_amdgcn_s_setprio(0);
        if (t + 1 < nt) { if constexpr (BMQ == 2) WAITV(4); else WAITV(3); }
        else { WAITV(0); }
        SBAR();
    }

    if constexpr (OUT_MODE == 2) {
        auto tr = (f16(*)[72])smraw;
        const int batch = (int)(rowA0 >> 11);
        const long long rib = rowA0 & 2047;
        const int c  = tid >> 1;
        const int r0 = (tid & 1) << 5;
#pragma unroll
        for (int h2 = 0; h2 < 2; h2++)
#pragma unroll
            for (int iq = 0; iq < 2; iq++) {
                __syncthreads();
                if (wm == h2) {
#pragma unroll
                    for (int i2 = 0; i2 < 4; i2++)
#pragma unroll
                        for (int j = 0; j < 4; j++)
#pragma unroll
                            for (int e = 0; e < 4; e++)
                                tr[wn * 64 + j * 16 + l16][i2 * 16 + quad * 4 + e] =
                                    (f16)acc[iq * 4 + i2][j][e];
                }
                __syncthreads();
                f16* vt = Ch + (long long)batch * 1024 * 2048 +
                          (long long)(colB0 + c) * ldc + rib + h2 * 128 + iq * 64 + r0;
#pragma unroll
                for (int u = 0; u < 32; u += 8)
                    *(f16x8*)(vt + u) = *(const f16x8*)&tr[c][r0 + u];
            }
        return;
    }

    const long long cOff = (long long)bz * sC +
                           (rowA0 + wm * (BMQ * 64) + quad * 4) * (long long)ldc +
                           colB0 + wn * 64 + l16;
#pragma unroll
    for (int i = 0; i < nI; i++)
#pragma unroll
        for (int e = 0; e < 4; e++) {
            const long long ro = cOff + (long long)(i * 16 + e) * ldc;
            if (OUT_MODE == 0) {
                float* rp = Cf + ro;
#pragma unroll
                for (int j = 0; j < 4; j++) rp[j * 16] = acc[i][j][e];
            } else {
                f16* rp = Ch + ro;
#pragma unroll
                for (int j = 0; j < 4; j++) rp[j * 16] = (f16)acc[i][j][e];
            }
        }
}

__global__ __launch_bounds__(512, 2) void tv8d(
    const f16* __restrict__ Xf, const f16* __restrict__ Mt_f,
    const f16* __restrict__ Wvt_f, f16* __restrict__ T, f16* __restrict__ Vt)
{
    extern __shared__ char smraw[];
    int bx = blockIdx.x, by = blockIdx.y;
    xcd_swz(256, 8, bx, by);
    if (bx < 4)
        gemm_deep_body<1, 2>(smraw, Xf, Mt_f, nullptr, T, 1024, 1024, 1024, 1024,
                             0, 0, 0, bx, by, 0);
    else
        gemm_deep_body<2, 2>(smraw, Xf, Wvt_f, nullptr, Vt, 1024, 1024, 1024, 2048,
                             0, 0, 0, bx - 4, by, 0);
}

template<int OUT_MODE, int BMQ>
__global__ __launch_bounds__(512, 2) void gemmd_k(
    const f16* __restrict__ A, const f16* __restrict__ B,
    float* __restrict__ Cf, f16* __restrict__ Ch,
    int K, int lda, int ldb, int ldc,
    long long sA, long long sB, long long sC)
{
    extern __shared__ char smraw[];
    int bx = blockIdx.x, by = blockIdx.y;
    xcd_swz(gridDim.x * gridDim.y, gridDim.x, bx, by);
    gemm_deep_body<OUT_MODE, BMQ>(smraw, A, B, Cf, Ch, K, lda, ldb, ldc,
                                  sA, sB, sC, bx, by, blockIdx.z);
}

// ============ 64KB fallback kernels (R13-verified; only if attrs fail) =====
template<int OUT_MODE, int BMQ>
__device__ __forceinline__ void gemm8_body(
    char* __restrict__ smraw,
    const f16* __restrict__ A, const f16* __restrict__ B,
    float* __restrict__ Cf, f16* __restrict__ Ch,
    int K, int lda, int ldb, int ldc,
    long long sA, long long sB, long long sC,
    int bx, int by, int bz)
{
    constexpr int B0OFF = BMQ * 8192;
    constexpr int B1OFF = B0OFF + 8192;
    constexpr int BUFSZ = B0OFF + 16384;

    A += (long long)bz * sA;
    B += (long long)bz * sB;

    const int tid  = threadIdx.x;
    const int lane = tid & 63;
    const int wave = tid >> 6;
    const int quad = lane >> 4;
    const int l16  = lane & 15;
    const int wm   = wave >> 2;
    const int wn   = wave & 3;

    const long long rowA0 = (long long)by * (BMQ * 128);
    const long long colB0 = (long long)bx * 256;

    const int line0 = tid >> 3;
    const int slog  = (tid & 7) ^ (line0 & 7);
    const int aRow0 = line0 * 2 + (slog >> 2);
    const int aCol0 = (slog & 3) * 8;
    const int bRow  = ((aRow0 >> 5) << 6) + (aRow0 & 31);

    const f16* aSrc0 = A + (rowA0 + aRow0) * lda + aCol0;
    const f16* aSrc1 = A + (rowA0 + 128 + aRow0) * lda + aCol0;
    const f16* b0Src = B + (colB0 + bRow) * ldb + aCol0;
    const f16* b1Src = b0Src + 32LL * ldb;

    const int dA0 = tid * 16, dA1 = 8192 + tid * 16;

    const int nt = K >> 5;

    auto stageA = [&](int t) {
        char* buf = smraw + (t & 1) * BUFSZ;
        async_load16(aSrc0 + t * 32, buf + dA0);
        if (BMQ == 2) async_load16(aSrc1 + t * 32, buf + dA1);
    };
    auto stageB0 = [&](int t) {
        char* buf = smraw + (t & 1) * BUFSZ;
        async_load16(b0Src + t * 32, buf + B0OFF + dA0);
    };
    auto stageB1 = [&](int t) {
        char* buf = smraw + (t & 1) * BUFSZ;
        async_load16(b1Src + t * 32, buf + B1OFF + dA0);
    };

    const int h    = l16 >> 1;
    const int lofs = h * 128 + ((((l16 & 1) * 4 + quad) ^ h) << 4);
    const int aoff = wm * (BMQ * 4096) + lofs;
    const int boff = wn * 2048 + lofs;

    f32x4 acc[4 * BMQ][4];
#pragma unroll
    for (int i = 0; i < 4 * BMQ; i++)
#pragma unroll
        for (int j = 0; j < 4; j++) acc[i][j] = (f32x4){0.f, 0.f, 0.f, 0.f};

    stageA(0); stageB0(0); stageB1(0);
    stageA(1); stageB0(1);
    if constexpr (BMQ == 2) WAITV(4); else WAITV(3);
    SBAR();

    for (int t = 0; t < nt; t++) {
        const char* buf = smraw + (t & 1) * BUFSZ;
        f16x8 av[4 * BMQ], bv[2];

#pragma unroll
        for (int i = 0; i < 4 * BMQ; i++) av[i] = *(const f16x8*)(buf + aoff + i * 1024);
#pragma unroll
        for (int j = 0; j < 2; j++) bv[j] = *(const f16x8*)(buf + B0OFF + boff + j * 1024);
        if (t + 1 < nt) stageB1(t + 1);
        SBAR();
        WAITL();
        __builtin_amdgcn_s_setprio(1);
#pragma unroll
        for (int i = 0; i < 4 * BMQ; i++) {
            acc[i][0] = mfma16(av[i], bv[0], acc[i][0]);
            acc[i][1] = mfma16(av[i], bv[1], acc[i][1]);
        }
        __builtin_amdgcn_s_setprio(0);
        if (t + 1 < nt) { if constexpr (BMQ == 2) WAITV(4); else WAITV(3); }
        else WAITV(0);
        SBAR();

#pragma unroll
        for (int j = 0; j < 2; j++) bv[j] = *(const f16x8*)(buf + B1OFF + boff + j * 1024);
        if (t + 2 < nt) { stageA(t + 2); stageB0(t + 2); }
        SBAR();
        WAITL();
        __builtin_amdgcn_s_setprio(1);
#pragma unroll
        for (int i = 0; i < 4 * BMQ; i++) {
            acc[i][2] = mfma16(av[i], bv[0], acc[i][2]);
            acc[i][3] = mfma16(av[i], bv[1], acc[i][3]);
        }
        __builtin_amdgcn_s_setprio(0);
        if (t + 2 < nt) { if constexpr (BMQ == 2) WAITV(4); else WAITV(3); }
        else if (t + 1 < nt) WAITV(1);
        SBAR();
    }

    if constexpr (OUT_MODE == 2) {
        auto tr = (f16(*)[72])smraw;
        const int batch = (int)(rowA0 >> 11);
        const long long rib = rowA0 & 2047;
        const int c  = tid >> 1;
        const int r0 = (tid & 1) << 5;
#pragma unroll
        for (int h2 = 0; h2 < 2; h2++)
#pragma unroll
            for (int iq = 0; iq < 2; iq++) {
                __syncthreads();
                if (wm == h2) {
#pragma unroll
                    for (int i2 = 0; i2 < 4; i2++)
#pragma unroll
                        for (int j = 0; j < 4; j++)
#pragma unroll
                            for (int e = 0; e < 4; e++)
                                tr[wn * 64 + j * 16 + l16][i2 * 16 + quad * 4 + e] =
                                    (f16)acc[iq * 4 + i2][j][e];
                }
                __syncthreads();
                f16* vt = Ch + (long long)batch * 1024 * 2048 +
                          (long long)(colB0 + c) * ldc + rib + h2 * 128 + iq * 64 + r0;
#pragma unroll
                for (int u = 0; u < 32; u += 8)
                    *(f16x8*)(vt + u) = *(const f16x8*)&tr[c][r0 + u];
            }
        return;
    }

    const long long cOff = (long long)bz * sC +
                           (rowA0 + wm * (BMQ * 64) + quad * 4) * (long long)ldc +
                           colB0 + wn * 64 + l16;
#pragma unroll
    for (int i = 0; i < 4 * BMQ; i++)
#pragma unroll
        for (int e = 0; e < 4; e++) {
            const long long ro = cOff + (long long)(i * 16 + e) * ldc;
            if (OUT_MODE == 0) {
                float* rp = Cf + ro;
#pragma unroll
                for (int j = 0; j < 4; j++) rp[j * 16] = acc[i][j][e];
            } else {
                f16* rp = Ch + ro;
#pragma unroll
                for (int j = 0; j < 4; j++) rp[j * 16] = (f16)acc[i][j][e];
            }
        }
}

__global__ __launch_bounds__(512, 2) void tv8(
    const f16* __restrict__ Xf, const f16* __restrict__ Mt_f,
    const f16* __restrict__ Wvt_f, f16* __restrict__ T, f16* __restrict__ Vt)
{
    extern __shared__ char smraw[];
    int bx = blockIdx.x, by = blockIdx.y;
    xcd_swz(256, 8, bx, by);
    if (bx < 4)
        gemm8_body<1, 2>(smraw, Xf, Mt_f, nullptr, T, 1024, 1024, 1024, 1024,
                         0, 0, 0, bx, by, 0);
    else
        gemm8_body<2, 2>(smraw, Xf, Wvt_f, nullptr, Vt, 1024, 1024, 1024, 2048,
                         0, 0, 0, bx - 4, by, 0);
}

template<int OUT_MODE, int BMQ>
__global__ __launch_bounds__(512, 2) void gemm8_k(
    const f16* __restrict__ A, const f16* __restrict__ B,
    float* __restrict__ Cf, f16* __restrict__ Ch,
    int K, int lda, int ldb, int ldc,
    long long sA, long long sB, long long sC)
{
    extern __shared__ char smraw[];
    int bx = blockIdx.x, by = blockIdx.y;
    xcd_swz(gridDim.x * gridDim.y, gridDim.x, bx, by);
    gemm8_body<OUT_MODE, BMQ>(smraw, A, B, Cf, Ch, K, lda, ldb, ldc, sA, sB, sC,
                              bx, by, blockIdx.z);
}

// ============== 128^2 kernel (Mt only: split-bf16 3-MFMA, gload_lds) =======
template<typename E, bool SPLIT, int OUT_MODE, int BK>
__device__ __forceinline__ void gemm_body(
    char* __restrict__ smraw,
    const E* __restrict__ Ahi, const E* __restrict__ Alo,
    const E* __restrict__ Bhi, const E* __restrict__ Blo,
    float* __restrict__ Cf, f16* __restrict__ Ch,
    int K, int lda, int ldb, int ldc,
    long long sA, long long sB, long long sC,
    int bx, int by, int bz)
{
    using vec8 = typename vec8_of<E>::type;
    constexpr int TILE_BYTES = 128 * BK * (int)sizeof(E);
    constexpr int CPW = (TILE_BYTES / 1024) / 4;
    constexpr int SPR = (BK * (int)sizeof(E)) / 16;

    Ahi += (long long)bz * sA;
    Bhi += (long long)bz * sB;
    if (SPLIT) { Alo += (long long)bz * sA; Blo += (long long)bz * sB; }

    const int tid  = threadIdx.x;
    const int lane = tid & 63;
    const int wave = tid >> 6;
    const int quad = lane >> 4;
    const int l16  = lane & 15;
    const int wm   = (wave >> 1) * 64;
    const int wn   = (wave & 1) * 64;

    const long long rowA0 = (long long)by * 128;
    const long long colB0 = (long long)bx * 128;

    auto swz = [](int r) -> int { return (SPR == 8) ? (r & 7) : ((r >> 1) & 3); };

    int ofs[CPW], rr[CPW], cc8[CPW];
#pragma unroll
    for (int u = 0; u < CPW; u++) {
        ofs[u] = (wave * CPW + u) * 1024 + lane * 16;
        const int s = ofs[u] >> 4;
        rr[u]  = s / SPR;
        cc8[u] = (s & (SPR - 1)) ^ swz(rr[u]);
    }

    f32x4 acc[4][4];
#pragma unroll
    for (int i = 0; i < 4; i++)
#pragma unroll
        for (int j = 0; j < 4; j++) acc[i][j] = (f32x4){0.f, 0.f, 0.f, 0.f};

    for (int k0 = 0; k0 < K; k0 += BK) {
#pragma unroll
        for (int u = 0; u < CPW; u++) {
            async_load16(Ahi + (rowA0 + rr[u]) * lda + k0 + cc8[u] * 8, smraw + 0 * TILE_BYTES + ofs[u]);
            async_load16(Bhi + (colB0 + rr[u]) * ldb + k0 + cc8[u] * 8, smraw + 1 * TILE_BYTES + ofs[u]);
            if (SPLIT) {
                async_load16(Alo + (rowA0 + rr[u]) * lda + k0 + cc8[u] * 8, smraw + 2 * TILE_BYTES + ofs[u]);
                async_load16(Blo + (colB0 + rr[u]) * ldb + k0 + cc8[u] * 8, smraw + 3 * TILE_BYTES + ofs[u]);
            }
        }
        __syncthreads();

#pragma unroll
        for (int kh = 0; kh < BK / 32; kh++) {
            const int kc8 = kh * 4 + quad;
            vec8 a_hi[4], b_hi[4], a_lo[4], b_lo[4];
#pragma unroll
            for (int i = 0; i < 4; i++) {
                const int ra = wm + i * 16 + l16;
                const int rb = wn + i * 16 + l16;
                const int oa = ra * (SPR * 16) + ((kc8 ^ swz(ra)) << 4);
                const int ob = rb * (SPR * 16) + ((kc8 ^ swz(rb)) << 4);
                a_hi[i] = *(const vec8*)(smraw + 0 * TILE_BYTES + oa);
                b_hi[i] = *(const vec8*)(smraw + 1 * TILE_BYTES + ob);
                if (SPLIT) {
                    a_lo[i] = *(const vec8*)(smraw + 2 * TILE_BYTES + oa);
                    b_lo[i] = *(const vec8*)(smraw + 3 * TILE_BYTES + ob);
                }
            }
#pragma unroll
            for (int i = 0; i < 4; i++)
#pragma unroll
                for (int j = 0; j < 4; j++) {
                    acc[i][j] = mfma16(a_hi[i], b_hi[j], acc[i][j]);
                    if (SPLIT) {
                        acc[i][j] = mfma16(a_hi[i], b_lo[j], acc[i][j]);
                        acc[i][j] = mfma16(a_lo[i], b_hi[j], acc[i][j]);
                    }
                }
        }
        __syncthreads();
    }

    const long long cOff = (long long)bz * sC +
                           (rowA0 + wm + quad * 4) * (long long)ldc + colB0 + wn + l16;
#pragma unroll
    for (int i = 0; i < 4; i++)
#pragma unroll
        for (int e = 0; e < 4; e++) {
            const long long ro = cOff + (i * 16 + e) * ldc;
            if (OUT_MODE == 0) {
                float* rp = Cf + ro;
#pragma unroll
                for (int j = 0; j < 4; j++) rp[j * 16] = acc[i][j][e];
            } else {
                f16* rp = Ch + ro;
#pragma unroll
                for (int j = 0; j < 4; j++) rp[j * 16] = (f16)acc[i][j][e];
            }
        }
}

template<typename E, bool SPLIT, int OUT_MODE, int BK>
__global__ __launch_bounds__(256) void gemm_bt(
    const E* __restrict__ Ahi, const E* __restrict__ Alo,
    const E* __restrict__ Bhi, const E* __restrict__ Blo,
    float* __restrict__ Cf, f16* __restrict__ Ch,
    int K, int lda, int ldb, int ldc,
    long long sA, long long sB, long long sC)
{
    extern __shared__ char smraw[];
    gemm_body<E, SPLIT, OUT_MODE, BK>(smraw, Ahi, Alo, Bhi, Blo, Cf, Ch,
                                      K, lda, ldb, ldc, sA, sB, sC,
                                      blockIdx.x, blockIdx.y, blockIdx.z);
}

// ---- D1: X->f16 || Wq,Wk bf16-split || Wv transpose->f16 ----
__global__ __launch_bounds__(256) void prep_all(
    const float4* __restrict__ X, f16* __restrict__ Xf,
    const float* __restrict__ Wq, const float* __restrict__ Wk, const float* __restrict__ Wv,
    bf16* __restrict__ Wq_h, bf16* __restrict__ Wq_l,
    bf16* __restrict__ Wk_h, bf16* __restrict__ Wk_l,
    f16* __restrict__ Wvt_f)
{
    typedef __bf16 bf16x4v __attribute__((ext_vector_type(4)));
    int b = blockIdx.x;
    if (b < 8192) {
        long long i = (long long)b * 256 + threadIdx.x;
        float4 v = X[i];
        f16x4 fv = {(f16)v.x, (f16)v.y, (f16)v.z, (f16)v.w};
        *(f16x4*)(Xf + 4 * i) = fv;
    } else if (b < 10240) {
        const int b2 = b - 8192;
        const float4* W = (const float4*)(b2 < 1024 ? Wq : Wk);
        bf16* hh = b2 < 1024 ? Wq_h : Wk_h;
        bf16* ll = b2 < 1024 ? Wq_l : Wk_l;
        long long i = (long long)(b2 & 1023) * 256 + threadIdx.x;
        float4 v = W[i];
        bf16 a0 = (bf16)v.x, a1 = (bf16)v.y, a2 = (bf16)v.z, a3 = (bf16)v.w;
        bf16x4v hv = {a0, a1, a2, a3};
        bf16x4v lv = {(bf16)(v.x - (float)a0), (bf16)(v.y - (float)a1),
                      (bf16)(v.z - (float)a2), (bf16)(v.w - (float)a3)};
        *(bf16x4v*)(hh + 4 * i) = hv;
        *(bf16x4v*)(ll + 4 * i) = lv;
    } else {
        const int b3 = b - 10240;
        __shared__ float t[32][33];
        const int bx = (b3 & 31) * 32, by = (b3 >> 5) * 32;
        const int tx = threadIdx.x & 31, ty = threadIdx.x >> 5;
#pragma unroll
        for (int i = 0; i < 32; i += 8)
            t[ty + i][tx] = Wv[(long long)(by + ty + i) * 1024 + bx + tx];
        __syncthreads();
#pragma unroll
        for (int i = 0; i < 32; i += 8) {
            long long o = (long long)(bx + ty + i) * 1024 + by + tx;
            Wvt_f[o] = (f16)t[tx][ty + i];
        }
    }
}

// ---- D5: row softmax fp32 -> f16, vectorized ----
__global__ __launch_bounds__(256) void softmax_f16(const float* __restrict__ S,
                                                   f16* __restrict__ P, int n)
{
    const long long row = blockIdx.x;
    const float4* p = (const float4*)(S + row * (long long)n);
    f16* q = P + row * (long long)n;
    const int tid = threadIdx.x;
    const int wv = tid >> 6, lane = tid & 63;

    float4 va = p[tid], vb = p[tid + 256];
    float v[8] = {va.x, va.y, va.z, va.w, vb.x, vb.y, vb.z, vb.w};
    float m = -3.4e38f;
#pragma unroll
    for (int i = 0; i < 8; i++) m = fmaxf(m, v[i]);
#pragma unroll
    for (int off = 32; off > 0; off >>= 1) m = fmaxf(m, __shfl_xor(m, off, 64));

    __shared__ float red[4];
    if (lane == 0) red[wv] = m;
    __syncthreads();
    m = fmaxf(fmaxf(red[0], red[1]), fmaxf(red[2], red[3]));

    float s = 0.f;
#pragma unroll
    for (int i = 0; i < 8; i++) { v[i] = __expf(v[i] - m); s += v[i]; }
#pragma unroll
    for (int off = 32; off > 0; off >>= 1) s += __shfl_xor(s, off, 64);
    __syncthreads();
    if (lane == 0) red[wv] = s;
    __syncthreads();
    s = red[0] + red[1] + red[2] + red[3];

    const float inv = 1.0f / s;
    f16x4 o0 = {(f16)(v[0] * inv), (f16)(v[1] * inv), (f16)(v[2] * inv), (f16)(v[3] * inv)};
    f16x4 o1 = {(f16)(v[4] * inv), (f16)(v[5] * inv), (f16)(v[6] * inv), (f16)(v[7] * inv)};
    *(f16x4*)(q + tid * 4) = o0;
    *(f16x4*)(q + 1024 + tid * 4) = o1;
}

extern "C" void kernel_launch(void* const* d_in, const int* in_sizes, int n_in,
                              void* d_out, int out_size, void* d_ws, size_t ws_size,
                              hipStream_t stream) {
    const float* X  = (const float*)d_in[0];   // [8192,1024]
    const float* Wq = (const float*)d_in[1];   // [1024,1024]
    const float* Wk = (const float*)d_in[2];
    const float* Wv = (const float*)d_in[3];
    float* out = (float*)d_out;                // [8192,1024]

    char* w = (char*)d_ws;
    const long long MB = 1024LL * 1024;
    f16*  Xf    = (f16*) (w + 0 * MB);     // 16 MB
    bf16* Wq_h  = (bf16*)(w + 16 * MB);    // 2 MB
    bf16* Wq_l  = (bf16*)(w + 18 * MB);
    bf16* Wk_h  = (bf16*)(w + 20 * MB);
    bf16* Wk_l  = (bf16*)(w + 22 * MB);
    f16*  Wvt_f = (f16*) (w + 24 * MB);    // 2 MB (transposed)
    f16*  Mt_f  = (f16*) (w + 26 * MB);    // 2 MB
    f16*  T     = (f16*) (w + 28 * MB);    // 16 MB [8192,1024]
    f16*  Vt    = (f16*) (w + 44 * MB);    // 16 MB [4][1024][2048]
    float* Sc   = (float*)(w + 60 * MB);   // 64 MB
    f16*  P     = (f16*) (w + 124 * MB);   // 32 MB -> ends 156 MB

    static int deep_ok = -1;
    if (deep_ok < 0) {
        auto* pSc = gemmd_k<0, 2>;
        auto* pPv = gemmd_k<0, 1>;
        hipError_t e1 = hipFuncSetAttribute(
            reinterpret_cast<const void*>(tv8d),
            hipFuncAttributeMaxDynamicSharedMemorySize, 131072);
        hipError_t e2 = hipFuncSetAttribute(
            reinterpret_cast<const void*>(pSc),
            hipFuncAttributeMaxDynamicSharedMemorySize, 131072);
        hipError_t e3 = hipFuncSetAttribute(
            reinterpret_cast<const void*>(pPv),
            hipFuncAttributeMaxDynamicSharedMemorySize, 98304);
        deep_ok = (e1 == hipSuccess && e2 == hipSuccess && e3 == hipSuccess) ? 1 : 0;
    }

    dim3 blk(256);

    // D1: prep
    prep_all<<<dim3(11264), blk, 0, stream>>>(
        (const float4*)X, Xf, Wq, Wk, Wv, Wq_h, Wq_l, Wk_h, Wk_l, Wvt_f);

    // D2: Mt = Wk_s Wq_s^T (split bf16, 3-MFMA) -> f16
    gemm_bt<bf16, true, 1, 32><<<dim3(8, 8, 1), blk, 32768, stream>>>(
        Wk_h, Wk_l, Wq_h, Wq_l, nullptr, Mt_f,
        1024, 1024, 1024, 1024, 0, 0, 0);

    if (deep_ok) {
        tv8d<<<dim3(8, 32), dim3(512), 131072, stream>>>(Xf, Mt_f, Wvt_f, T, Vt);
        gemmd_k<0, 2><<<dim3(8, 8, 4), dim3(512), 131072, stream>>>(
            T, Xf, Sc, nullptr, 1024, 1024, 1024, 2048,
            2048LL * 1024, 2048LL * 1024, 2048LL * 2048);
        softmax_f16<<<dim3(4 * 2048), blk, 0, stream>>>(Sc, P, 2048);
        gemmd_k<0, 1><<<dim3(4, 16, 4), dim3(512), 98304, stream>>>(
            P, Vt, out, nullptr, 2048, 2048, 2048, 1024,
            2048LL * 2048, 1024LL * 2048, 2048LL * 1024);
    } else {
        tv8<<<dim3(8, 32), dim3(512), 65536, stream>>>(Xf, Mt_f, Wvt_f, T, Vt);
        gemm8_k<0, 2><<<dim3(8, 8, 4), dim3(512), 65536, stream>>>(
            T, Xf, Sc, nullptr, 1024, 1024, 1024, 2048,
            2048LL * 1024, 2048LL * 1024, 2048LL * 2048);
        softmax_f16<<<dim3(4 * 2048), blk, 0, stream>>>(Sc, P, 2048);
        gemm8_k<0, 1><<<dim3(4, 16, 4), dim3(512), 49152, stream>>>(
            P, Vt, out, nullptr, 2048, 2048, 2048, 1024,
            2048LL * 2048, 1024LL * 2048, 2048LL * 1024);
    }
}